// Round 12
// baseline (588.051 us; speedup 1.0000x reference)
//
#include <hip/hip_runtime.h>

static constexpr int NN = 50000;      // nodes
static constexpr int NE = 800000;     // edges
static constexpr int DEMB = 512;
static constexpr int QKV_OUT = 1536;  // (2*64+64)*8

typedef _Float16 half8 __attribute__((ext_vector_type(8)));
typedef float floatx4 __attribute__((ext_vector_type(4)));

// K/V int8 quantization: values ~ N(0,1); clamp at 5.5 sigma (P ~ 4e-8)
#define KQ_SCALE (127.0f / 5.5f)
#define KQ_DEQ   (5.5f / 127.0f)

// ---------------- workspace layout (bytes) ----------------
static constexpr size_t OFF_QH   = 0;                    // N*512 f16 = 51,200,000
static constexpr size_t OFF_K8   = 51200000;             // N*512 i8  = 25,600,000
static constexpr size_t OFF_V8   = 76800000;             // N*512 i8  = 25,600,000
static constexpr size_t OFF_MSG  = 102400000;            // N*512 f16 = 51,200,000 (aliases xh)
static constexpr size_t OFF_SRT  = 153600000;            // E i32     =  3,200,000
static constexpr size_t OFF_DEG  = 156800000;            // N i32
static constexpr size_t OFF_OFFA = 157000000;            // (N+1) i32
static constexpr size_t OFF_CUR  = 157200064;            // N i32
static constexpr size_t OFF_FLAG = 157400064;            // 1 i32
static constexpr size_t OFF_WQH  = 157400128;            // 1536*512 f16 = 1,572,864
static constexpr size_t OFF_WFH  = 158972992;            // 512*512 f16  =   524,288

typedef __attribute__((address_space(1))) const void* gas_ptr;
typedef __attribute__((address_space(3))) void* lds_ptr_t;

__device__ __forceinline__ void load_lds16(const void* g, void* l) {
  __builtin_amdgcn_global_load_lds((gas_ptr)g, (lds_ptr_t)l, 16, 0, 0);
}

// ---------------- f32 -> f16 convert ----------------
__global__ __launch_bounds__(256)
void k_cvt(const float* __restrict__ in, _Float16* __restrict__ out, int n8) {
  int i = blockIdx.x * 256 + threadIdx.x;
  if (i < n8) {
    floatx4 a = *(const floatx4*)(in + (size_t)i * 8);
    floatx4 b = *(const floatx4*)(in + (size_t)i * 8 + 4);
    half8 h;
    #pragma unroll
    for (int q = 0; q < 4; ++q) { h[q] = (_Float16)a[q]; h[q + 4] = (_Float16)b[q]; }
    *(half8*)(out + (size_t)i * 8) = h;
  }
}

// ---------------- edge dtype detection (int32 vs int64) ----------------
__global__ __launch_bounds__(64)
void k_detect64(const void* __restrict__ edge, int* __restrict__ flag) {
  if (threadIdx.x == 0) {
    const int* p = (const int*)edge;
    int is64 = 1;
    for (int i = 0; i < 16; ++i) if (p[2 * i + 1] != 0) is64 = 0;
    *flag = is64;
  }
}

__device__ __forceinline__ int edge_at(const void* edge, int row, int e, int is64) {
  if (is64) return (int)((const long long*)edge)[(size_t)row * NE + e];
  return ((const int*)edge)[(size_t)row * NE + e];
}

// ---------------- CSR build ----------------
__global__ __launch_bounds__(256)
void k_histo(const void* __restrict__ edge, const int* __restrict__ flag,
             int* __restrict__ deg) {
  int e = blockIdx.x * 256 + threadIdx.x;
  if (e < NE) {
    int r = edge_at(edge, 1, e, *flag);
    atomicAdd(&deg[r], 1);
  }
}

__global__ __launch_bounds__(1024)
void k_scan(const int* __restrict__ deg, int* __restrict__ off,
            int* __restrict__ cur, int n) {
  __shared__ int sums[1024];
  int tid = threadIdx.x;
  int per = (n + 1023) >> 10;
  int start = tid * per;
  int end = start + per; if (end > n) end = n;
  int s = 0;
  for (int i = start; i < end; ++i) s += deg[i];
  sums[tid] = s;
  __syncthreads();
  for (int d = 1; d < 1024; d <<= 1) {
    int v = (tid >= d) ? sums[tid - d] : 0;
    __syncthreads();
    sums[tid] += v;
    __syncthreads();
  }
  int run = (tid == 0) ? 0 : sums[tid - 1];
  for (int i = start; i < end; ++i) {
    off[i] = run; cur[i] = run; run += deg[i];
  }
  if (tid == 0) off[n] = sums[1023];
}

__global__ __launch_bounds__(256)
void k_scatter(const void* __restrict__ edge, const int* __restrict__ flag,
               int* __restrict__ cur, int* __restrict__ srt) {
  int e = blockIdx.x * 256 + threadIdx.x;
  if (e < NE) {
    int is64 = *flag;
    int r = edge_at(edge, 1, e, is64);
    int s = edge_at(edge, 0, e, is64);
    int pos = atomicAdd(&cur[r], 1);
    srt[pos] = s;
  }
}

// ---------------- GEMM (NT) 256x256, BK=64, 512 thr, m201 8-phase schedule ---------
// C[m,n] = sum_k A[m,k]*B[n,k] + bias[n]; A,B f16 row-major.
// MODE 0: QKV epilogue — region gn>>9: 0->Qh f16, 1->K8 int8, 2->V8 int8.
// MODE 1: plain f32 C[M][N].
// LDS: [2 buf][A|B][2 kk][256 rows x 32 k] 16KB chunks (128 KiB). 8 waves (2Mx4N),
// wave tile 128x64. 4 phases per K-tile (quadrant = kk-half x n-half), 16 MFMA each:
//   q0: rd a[m0-7]kk0 (8 ds) + b[n0-1]kk0 (2 ds); STAGE B-kk1(t+1)
//   q1: rd b[n2-3]kk0 (2 ds, a reused);           STAGE A-kk0(t+2)
//   q2: rd a[m0-7]kk1 + b[n0-1]kk1;               STAGE B-kk0(t+2)
//   q3: rd b[n2-3]kk1;                             STAGE A-kk1(t+2)
// each phase: reads+stage -> s_barrier -> lgkmcnt(0) -> setprio1 -> 16 MFMA ->
// setprio0 -> s_barrier.  vmcnt(6) ONCE per tile at END of q3 (before the closing
// barrier -> all waves drained before any wave reads the next tile's chunks);
// tail tiles use vmcnt(0). Register reuse frees each LDS chunk after one phase,
// which is what legalizes staging t+2 into the buffer being read (t+2 = t mod 2).
// Swizzle: stored 16B slot s holds global chunk s^((row>>1)&3), both sides
// (R6-verified conflict-free). Accumulation order identical to the R8 kernel
// (per-acc k ascending) -> output must be bitwise identical.
template<int MODE>
__global__ __launch_bounds__(512, 2)
void k_gemm8p(const _Float16* __restrict__ Ah, const _Float16* __restrict__ Bh,
              const float* __restrict__ bias,
              void* __restrict__ out0, void* __restrict__ out1, void* __restrict__ out2,
              int M, int N, int K, int nxt) {
  __shared__ _Float16 lds[2][2][2][256 * 32];   // [buf][A/B][kk][row*32+k] = 128 KiB
  const int tid = threadIdx.x;

  // XCD-chunked swizzle (nwg multiple of 8), n-fastest inside chunk
  const int nwg = gridDim.x;
  const int cpx = nwg >> 3;
  const int w = (blockIdx.x & 7) * cpx + (blockIdx.x >> 3);
  const int m0 = (w / nxt) * 256;
  const int n0 = (w % nxt) * 256;

  const int wid = tid >> 6, lane = tid & 63;
  const int wr = wid >> 2, wc = wid & 3;     // 2 x 4 wave grid; wave out 128x64

  floatx4 acc[8][4];
  #pragma unroll
  for (int m = 0; m < 8; ++m)
    #pragma unroll
    for (int n = 0; n < 4; ++n)
      #pragma unroll
      for (int q = 0; q < 4; ++q) acc[m][n][q] = 0.f;

  // staging: thread covers chunk rows (tid>>2) and (tid>>2)+128, stored slot tid&3;
  // source 16B chunk = (tid&3)^((row>>1)&3)  ((row+128)>>1 == row>>1 mod 4).
  const int srow = tid >> 2;                              // 0..127
  const int schunk = (tid & 3) ^ ((srow >> 1) & 3);
  int garow0 = m0 + srow;        if (garow0 >= M) garow0 = M - 1;
  int garow1 = m0 + 128 + srow;  if (garow1 >= M) garow1 = M - 1;
  const int gbrow0 = n0 + srow, gbrow1 = n0 + 128 + srow; // N mult of 256

  const int fr = lane & 15;
  const int fs = lane >> 4;                  // 0..3 (16B slot along the 32-k chunk)

  const int KT = K >> 6;                     // K-tiles of 64 (KT=8 here, even)

  auto STAGE = [&](int t, int mat, int kk) {
    char* dst = (char*)&lds[t & 1][mat][kk][0];
    const size_t kb = (size_t)t * 64 + kk * 32 + schunk * 8;
    if (mat == 0) {
      load_lds16(Ah + (size_t)garow0 * K + kb, dst + tid * 16);
      load_lds16(Ah + (size_t)garow1 * K + kb, dst + 8192 + tid * 16);
    } else {
      load_lds16(Bh + (size_t)gbrow0 * K + kb, dst + tid * 16);
      load_lds16(Bh + (size_t)gbrow1 * K + kb, dst + 8192 + tid * 16);
    }
  };
  auto RD_A = [&](half8* a, const _Float16* La) {
    #pragma unroll
    for (int m = 0; m < 8; ++m) {
      int R = wr * 128 + m * 16 + fr;
      a[m] = *(const half8*)(La + R * 32 + ((fs ^ ((R >> 1) & 3)) << 3));
    }
  };
  auto RD_B = [&](half8* b, const _Float16* Lb, int nh) {
    #pragma unroll
    for (int n = 0; n < 2; ++n) {
      int R = wc * 64 + (nh * 2 + n) * 16 + fr;
      b[n] = *(const half8*)(Lb + R * 32 + ((fs ^ ((R >> 1) & 3)) << 3));
    }
  };

  // prologue: 7 chunks in steady-state order; drain tile 0's four (keep 3 in flight)
  STAGE(0, 0, 0); STAGE(0, 1, 0); STAGE(0, 0, 1); STAGE(0, 1, 1);
  STAGE(1, 0, 0); STAGE(1, 1, 0); STAGE(1, 0, 1);
  asm volatile("s_waitcnt vmcnt(6)" ::: "memory");
  __builtin_amdgcn_s_barrier();

  half8 a[8], b[2];
  for (int t = 0; t < KT; ++t) {
    const _Float16* La0 = &lds[t & 1][0][0][0];
    const _Float16* La1 = &lds[t & 1][0][1][0];
    const _Float16* Lb0 = &lds[t & 1][1][0][0];
    const _Float16* Lb1 = &lds[t & 1][1][1][0];
    // ---- q0: (kk0, n0-1) ----
    RD_A(a, La0);
    RD_B(b, Lb0, 0);
    if (t + 1 < KT) STAGE(t + 1, 1, 1);
    __builtin_amdgcn_s_barrier();
    asm volatile("s_waitcnt lgkmcnt(0)");
    __builtin_amdgcn_s_setprio(1);
    #pragma unroll
    for (int m = 0; m < 8; ++m) {
      acc[m][0] = __builtin_amdgcn_mfma_f32_16x16x32_f16(a[m], b[0], acc[m][0], 0, 0, 0);
      acc[m][1] = __builtin_amdgcn_mfma_f32_16x16x32_f16(a[m], b[1], acc[m][1], 0, 0, 0);
    }
    __builtin_amdgcn_s_setprio(0);
    __builtin_amdgcn_s_barrier();
    // ---- q1: (kk0, n2-3) ----
    RD_B(b, Lb0, 1);
    if (t + 2 < KT) STAGE(t + 2, 0, 0);
    __builtin_amdgcn_s_barrier();
    asm volatile("s_waitcnt lgkmcnt(0)");
    __builtin_amdgcn_s_setprio(1);
    #pragma unroll
    for (int m = 0; m < 8; ++m) {
      acc[m][2] = __builtin_amdgcn_mfma_f32_16x16x32_f16(a[m], b[0], acc[m][2], 0, 0, 0);
      acc[m][3] = __builtin_amdgcn_mfma_f32_16x16x32_f16(a[m], b[1], acc[m][3], 0, 0, 0);
    }
    __builtin_amdgcn_s_setprio(0);
    __builtin_amdgcn_s_barrier();
    // ---- q2: (kk1, n0-1) ----
    RD_A(a, La1);
    RD_B(b, Lb1, 0);
    if (t + 2 < KT) STAGE(t + 2, 1, 0);
    __builtin_amdgcn_s_barrier();
    asm volatile("s_waitcnt lgkmcnt(0)");
    __builtin_amdgcn_s_setprio(1);
    #pragma unroll
    for (int m = 0; m < 8; ++m) {
      acc[m][0] = __builtin_amdgcn_mfma_f32_16x16x32_f16(a[m], b[0], acc[m][0], 0, 0, 0);
      acc[m][1] = __builtin_amdgcn_mfma_f32_16x16x32_f16(a[m], b[1], acc[m][1], 0, 0, 0);
    }
    __builtin_amdgcn_s_setprio(0);
    __builtin_amdgcn_s_barrier();
    // ---- q3: (kk1, n2-3) ----
    RD_B(b, Lb1, 1);
    if (t + 2 < KT) STAGE(t + 2, 0, 1);
    __builtin_amdgcn_s_barrier();
    asm volatile("s_waitcnt lgkmcnt(0)");
    __builtin_amdgcn_s_setprio(1);
    #pragma unroll
    for (int m = 0; m < 8; ++m) {
      acc[m][2] = __builtin_amdgcn_mfma_f32_16x16x32_f16(a[m], b[0], acc[m][2], 0, 0, 0);
      acc[m][3] = __builtin_amdgcn_mfma_f32_16x16x32_f16(a[m], b[1], acc[m][3], 0, 0, 0);
    }
    __builtin_amdgcn_s_setprio(0);
    // counted drain for the NEXT tile's reads: all waves wait BEFORE the closing
    // barrier -> after it, every wave's chunks for tile t+1 have landed.
    if (t + 2 < KT) asm volatile("s_waitcnt vmcnt(6)" ::: "memory");
    else            asm volatile("s_waitcnt vmcnt(0)" ::: "memory");
    __builtin_amdgcn_s_barrier();
  }

  // epilogue: C/D layout col=lane&15, row=(lane>>4)*4+q  [m89/m91 verified]
  const int fq = fs << 2;
  #pragma unroll
  for (int m = 0; m < 8; ++m) {
    #pragma unroll
    for (int n = 0; n < 4; ++n) {
      int gn = n0 + wc * 64 + n * 16 + fr;
      float bv = bias[gn];
      #pragma unroll
      for (int q = 0; q < 4; ++q) {
        int gm = m0 + wr * 128 + m * 16 + fq + q;
        if (gm < M) {
          float val = acc[m][n][q] + bv;
          if (MODE == 0) {
            int region = gn >> 9;
            int col = gn & 511;
            size_t idx = (size_t)gm * 512 + col;
            if (region == 0) ((_Float16*)out0)[idx] = (_Float16)val;
            else {
              float s = fminf(fmaxf(val * KQ_SCALE, -127.f), 127.f);
              signed char c = (signed char)__float2int_rn(s);
              if (region == 1) ((signed char*)out1)[idx] = c;
              else             ((signed char*)out2)[idx] = c;
            }
          } else {
            ((float*)out0)[(size_t)gm * N + gn] = val;
          }
        }
      }
    }
  }
}

// ---------------- attention aggregation: one wave per receiver ----------------
// Qh [N][512] f16 ; K8/V8 [N][512] int8 (scale 5.5/127). Per-edge gather 1KB.
// 4-edge-deep gather pipeline + index prefetch.
__global__ __launch_bounds__(256)
void k_attn(const _Float16* __restrict__ Qh, const signed char* __restrict__ K8,
            const signed char* __restrict__ V8, const int* __restrict__ off,
            const int* __restrict__ srt, _Float16* __restrict__ msg) {
  int r = blockIdx.x * 4 + (threadIdx.x >> 6);
  if (r >= NN) return;
  int lane = threadIdx.x & 63;
  int h = lane >> 3, j = lane & 7;
  int qoff = h * 64 + j * 8;     // this lane's 8 dims of head h

  half8 qh = *(const half8*)(Qh + (size_t)r * 512 + qoff);
  float q[8];
  #pragma unroll
  for (int i = 0; i < 8; ++i) q[i] = (float)qh[i] * 0.125f * KQ_DEQ;  // 1/sqrt(64) * K dequant

  float denom = 0.f;
  float acc[8];
  #pragma unroll
  for (int i = 0; i < 8; ++i) acc[i] = 0.f;

  int e0 = off[r], e1 = off[r + 1];
  if (e1 <= e0) {  // no incoming edges: output zeros
    half8 z = {};
    *(half8*)(msg + (size_t)r * 512 + qoff) = z;
    return;
  }

  auto gload = [&](uint2& k8, uint2& v8, int s) {
    k8 = *(const uint2*)(K8 + (size_t)s * 512 + qoff);
    v8 = *(const uint2*)(V8 + (size_t)s * 512 + qoff);
  };
  auto consume = [&](uint2 k8, uint2 v8) {
    int xw = (int)k8.x, yw = (int)k8.y;
    float p = 0.f;
    p += q[0] * (float)((xw << 24) >> 24);
    p += q[1] * (float)((xw << 16) >> 24);
    p += q[2] * (float)((xw << 8) >> 24);
    p += q[3] * (float)(xw >> 24);
    p += q[4] * (float)((yw << 24) >> 24);
    p += q[5] * (float)((yw << 16) >> 24);
    p += q[6] * (float)((yw << 8) >> 24);
    p += q[7] * (float)(yw >> 24);
    p += __shfl_xor(p, 1);
    p += __shfl_xor(p, 2);
    p += __shfl_xor(p, 4);
    float w = __expf(p);   // exact softmax sans max-shift (scores ~N(0,1))
    denom += w;
    int vx = (int)v8.x, vy = (int)v8.y;
    acc[0] += w * (float)((vx << 24) >> 24);
    acc[1] += w * (float)((vx << 16) >> 24);
    acc[2] += w * (float)((vx << 8) >> 24);
    acc[3] += w * (float)(vx >> 24);
    acc[4] += w * (float)((vy << 24) >> 24);
    acc[5] += w * (float)((vy << 16) >> 24);
    acc[6] += w * (float)((vy << 8) >> 24);
    acc[7] += w * (float)(vy >> 24);
  };
  auto sidx = [&](int e) { return srt[e < e1 ? e : e1 - 1]; };

  uint2 kb0, kb1, kb2, kb3, vb0, vb1, vb2, vb3;
  gload(kb0, vb0, sidx(e0));
  gload(kb1, vb1, sidx(e0 + 1));
  gload(kb2, vb2, sidx(e0 + 2));
  gload(kb3, vb3, sidx(e0 + 3));
  int sn0 = sidx(e0 + 4), sn1 = sidx(e0 + 5), sn2 = sidx(e0 + 6), sn3 = sidx(e0 + 7);

  int e = e0;
  for (; e + 4 <= e1; e += 4) {
    consume(kb0, vb0); gload(kb0, vb0, sn0);
    consume(kb1, vb1); gload(kb1, vb1, sn1);
    consume(kb2, vb2); gload(kb2, vb2, sn2);
    consume(kb3, vb3); gload(kb3, vb3, sn3);
    sn0 = sidx(e + 8); sn1 = sidx(e + 9); sn2 = sidx(e + 10); sn3 = sidx(e + 11);
  }
  int rem = e1 - e;
  if (rem > 0) consume(kb0, vb0);
  if (rem > 1) consume(kb1, vb1);
  if (rem > 2) consume(kb2, vb2);

  float inv = KQ_DEQ / denom;   // fold V dequant into the normalization
  half8 oh;
  #pragma unroll
  for (int i = 0; i < 8; ++i) oh[i] = (_Float16)(acc[i] * inv);
  *(half8*)(msg + (size_t)r * 512 + qoff) = oh;
}

// ---------------- launcher ----------------
extern "C" void kernel_launch(void* const* d_in, const int* in_sizes, int n_in,
                              void* d_out, int out_size, void* d_ws, size_t ws_size,
                              hipStream_t stream) {
  const float* x     = (const float*)d_in[0];
  const void*  edge  = d_in[1];
  const float* W_qkv = (const float*)d_in[2];
  const float* b_qkv = (const float*)d_in[3];
  const float* W_ff  = (const float*)d_in[4];
  const float* b_ff  = (const float*)d_in[5];
  float* out = (float*)d_out;

  char* ws = (char*)d_ws;
  _Float16* Qh = (_Float16*)(ws + OFF_QH);
  signed char* K8 = (signed char*)(ws + OFF_K8);
  signed char* V8 = (signed char*)(ws + OFF_V8);
  _Float16* msgb = (_Float16*)(ws + OFF_MSG);   // aliases xh (disjoint lifetimes)
  _Float16* xh   = (_Float16*)(ws + OFF_MSG);
  int* srt  = (int*)(ws + OFF_SRT);
  int* deg  = (int*)(ws + OFF_DEG);
  int* offa = (int*)(ws + OFF_OFFA);
  int* cur  = (int*)(ws + OFF_CUR);
  int* flag = (int*)(ws + OFF_FLAG);
  _Float16* wqh = (_Float16*)(ws + OFF_WQH);
  _Float16* wfh = (_Float16*)(ws + OFF_WFH);

  hipMemsetAsync(deg, 0, NN * sizeof(int), stream);
  k_detect64<<<1, 64, 0, stream>>>(edge, flag);

  // f32 -> f16 conversions (x, W_qkv, W_ff)
  k_cvt<<<(NN * DEMB / 8 + 255) / 256, 256, 0, stream>>>(x, xh, NN * DEMB / 8);
  k_cvt<<<(QKV_OUT * DEMB / 8 + 255) / 256, 256, 0, stream>>>(W_qkv, wqh, QKV_OUT * DEMB / 8);
  k_cvt<<<(DEMB * DEMB / 8 + 255) / 256, 256, 0, stream>>>(W_ff, wfh, DEMB * DEMB / 8);

  // QKV projection -> split Qh(f16)/K8(int8)/V8(int8), each [N][512]
  // grid 196 m x 6 n = 1176 = 147*8 (divisible by 8 for the XCD swizzle)
  k_gemm8p<0><<<1176, 512, 0, stream>>>(
      xh, wqh, b_qkv, Qh, K8, V8, NN, QKV_OUT, DEMB, 6);

  k_histo<<<(NE + 255) / 256, 256, 0, stream>>>(edge, flag, deg);
  k_scan<<<1, 1024, 0, stream>>>(deg, offa, cur, NN);
  k_scatter<<<(NE + 255) / 256, 256, 0, stream>>>(edge, flag, cur, srt);

  // per-receiver online softmax + weighted V aggregation -> f16 [N,512]
  k_attn<<<(NN + 3) / 4, 256, 0, stream>>>(Qh, K8, V8, offa, srt, msgb);

  // output projection: [N,512] x [512,512]^T -> f32 d_out
  // grid 196 x 2 = 392 = 49*8
  k_gemm8p<1><<<392, 512, 0, stream>>>(
      msgb, wfh, b_ff, out, nullptr, nullptr, NN, DEMB, DEMB, 2);
}

// Round 13
// 571.653 us; speedup vs baseline: 1.0287x; 1.0287x over previous
//
#include <hip/hip_runtime.h>

static constexpr int NN = 50000;      // nodes
static constexpr int NE = 800000;     // edges
static constexpr int DEMB = 512;
static constexpr int QKV_OUT = 1536;  // (2*64+64)*8

typedef _Float16 half8 __attribute__((ext_vector_type(8)));
typedef float floatx4 __attribute__((ext_vector_type(4)));

// K/V int8 quantization: values ~ N(0,1); clamp at 5.5 sigma (P ~ 4e-8)
#define KQ_SCALE (127.0f / 5.5f)
#define KQ_DEQ   (5.5f / 127.0f)

// ---------------- workspace layout (bytes) ----------------
static constexpr size_t OFF_QH   = 0;                    // N*512 f16 = 51,200,000
static constexpr size_t OFF_KV8  = 51200000;             // N*1024 i8 = 51,200,000 (K/V interleaved 8B:8B)
static constexpr size_t OFF_MSG  = 102400000;            // N*512 f16 = 51,200,000 (aliases xh)
static constexpr size_t OFF_SRT  = 153600000;            // E i32     =  3,200,000
static constexpr size_t OFF_DEG  = 156800000;            // N i32
static constexpr size_t OFF_OFFA = 157000000;            // (N+1) i32
static constexpr size_t OFF_CUR  = 157200064;            // N i32
static constexpr size_t OFF_FLAG = 157400064;            // 1 i32
static constexpr size_t OFF_WQH  = 157400128;            // 1536*512 f16 = 1,572,864
static constexpr size_t OFF_WFH  = 158972992;            // 512*512 f16  =   524,288

typedef __attribute__((address_space(1))) const void* gas_ptr;
typedef __attribute__((address_space(3))) void* lds_ptr_t;

__device__ __forceinline__ void load_lds16(const void* g, void* l) {
  __builtin_amdgcn_global_load_lds((gas_ptr)g, (lds_ptr_t)l, 16, 0, 0);
}

// ---------------- f32 -> f16 convert ----------------
__global__ __launch_bounds__(256)
void k_cvt(const float* __restrict__ in, _Float16* __restrict__ out, int n8) {
  int i = blockIdx.x * 256 + threadIdx.x;
  if (i < n8) {
    floatx4 a = *(const floatx4*)(in + (size_t)i * 8);
    floatx4 b = *(const floatx4*)(in + (size_t)i * 8 + 4);
    half8 h;
    #pragma unroll
    for (int q = 0; q < 4; ++q) { h[q] = (_Float16)a[q]; h[q + 4] = (_Float16)b[q]; }
    *(half8*)(out + (size_t)i * 8) = h;
  }
}

// ---------------- edge dtype detection (int32 vs int64) ----------------
__global__ __launch_bounds__(64)
void k_detect64(const void* __restrict__ edge, int* __restrict__ flag) {
  if (threadIdx.x == 0) {
    const int* p = (const int*)edge;
    int is64 = 1;
    for (int i = 0; i < 16; ++i) if (p[2 * i + 1] != 0) is64 = 0;
    *flag = is64;
  }
}

__device__ __forceinline__ int edge_at(const void* edge, int row, int e, int is64) {
  if (is64) return (int)((const long long*)edge)[(size_t)row * NE + e];
  return ((const int*)edge)[(size_t)row * NE + e];
}

// ---------------- CSR build (scan + scatter; histo is fused into the QKV GEMM) ----
__global__ __launch_bounds__(1024)
void k_scan(const int* __restrict__ deg, int* __restrict__ off,
            int* __restrict__ cur, int n) {
  __shared__ int sums[1024];
  int tid = threadIdx.x;
  int per = (n + 1023) >> 10;
  int start = tid * per;
  int end = start + per; if (end > n) end = n;
  int s = 0;
  for (int i = start; i < end; ++i) s += deg[i];
  sums[tid] = s;
  __syncthreads();
  for (int d = 1; d < 1024; d <<= 1) {
    int v = (tid >= d) ? sums[tid - d] : 0;
    __syncthreads();
    sums[tid] += v;
    __syncthreads();
  }
  int run = (tid == 0) ? 0 : sums[tid - 1];
  for (int i = start; i < end; ++i) {
    off[i] = run; cur[i] = run; run += deg[i];
  }
  if (tid == 0) off[n] = sums[1023];
}

__global__ __launch_bounds__(256)
void k_scatter(const void* __restrict__ edge, const int* __restrict__ flag,
               int* __restrict__ cur, int* __restrict__ srt) {
  int e = blockIdx.x * 256 + threadIdx.x;
  if (e < NE) {
    int is64 = *flag;
    int r = edge_at(edge, 1, e, is64);
    int s = edge_at(edge, 0, e, is64);
    int pos = atomicAdd(&cur[r], 1);
    srt[pos] = s;
  }
}

// ---------------- QKV GEMM (NT) 256x256, BK=64, 512 thr, 2-phase (R8-exact) --------
// + FUSED edge histogram: blocks >= gemmBlocks do deg[] atomics (runs in the
//   GEMM's scheduling tail where CUs would otherwise idle).
// C[m,n] = sum_k A[m,k]*B[n,k] + bias[n]; A,B f16 row-major.
// Epilogue: region gn>>9: 0 -> Qh f16 [row][512];
//   1 -> K int8 into KV8[row*1024 + (d>>3)*16 + (d&7)]
//   2 -> V int8 into KV8[row*1024 + (d>>3)*16 + 8 + (d&7)]   (8B K : 8B V interleave)
// LDS ring [2 buf][2 kk][A|B] 16KB chunks; per kk: STAGE next tile's kk-half,
// compute, vmcnt(4)+s_barrier (counted: keeps the other half's 4 loads in flight).
// Swizzle: stored 16B slot s holds global chunk s^((row>>1)&3), both sides
// (R6-verified conflict-free).
__global__ __launch_bounds__(512, 2)
void k_qkv(const _Float16* __restrict__ Ah, const _Float16* __restrict__ Bh,
           const float* __restrict__ bias,
           _Float16* __restrict__ Qh, unsigned char* __restrict__ KV8,
           const void* __restrict__ edge, const int* __restrict__ flag,
           int* __restrict__ deg,
           int M, int N, int K, int nxt, int gemmBlocks) {
  __shared__ _Float16 lds[2][2][2][256 * 32];   // [buf][kk][A/B] = 128 KiB
  const int tid = threadIdx.x;

  if (blockIdx.x >= gemmBlocks) {   // -------- fused histogram part --------
    int e = (blockIdx.x - gemmBlocks) * 512 + tid;
    if (e < NE) {
      int r = edge_at(edge, 1, e, *flag);
      atomicAdd(&deg[r], 1);
    }
    return;
  }

  // XCD-chunked swizzle over the GEMM portion (gemmBlocks multiple of 8)
  const int cpx = gemmBlocks >> 3;
  const int w = (blockIdx.x & 7) * cpx + (blockIdx.x >> 3);
  const int m0 = (w / nxt) * 256;
  const int n0 = (w % nxt) * 256;

  const int wid = tid >> 6, lane = tid & 63;
  const int wr = wid >> 2, wc = wid & 3;     // 2 x 4 wave grid

  floatx4 acc[8][4];
  #pragma unroll
  for (int m = 0; m < 8; ++m)
    #pragma unroll
    for (int n = 0; n < 4; ++n)
      #pragma unroll
      for (int q = 0; q < 4; ++q) acc[m][n][q] = 0.f;

  const int srow = tid >> 2;                        // 0..127
  const int schunk = (tid & 3) ^ ((tid >> 3) & 3);  // source 16B chunk (pre-swizzle)
  int garow[2];
  #pragma unroll
  for (int c = 0; c < 2; ++c) {
    int gr = m0 + c * 128 + srow;
    garow[c] = gr < M ? gr : M - 1;                 // clamp; masked at store
  }
  const int gbrow0 = n0 + srow, gbrow1 = n0 + 128 + srow;  // N mult of 256

  const int fr = lane & 15;
  const int fs = lane >> 4;                  // 0..3 (16B slots along the 32-k)

  const int KT = K >> 6;

  auto STAGE = [&](int tt, int kk) {
    const size_t kbase = (size_t)tt * 64 + kk * 32 + schunk * 8;
    char* La = (char*)&lds[tt & 1][kk][0][0];
    char* Lb = (char*)&lds[tt & 1][kk][1][0];
    load_lds16(Ah + (size_t)garow[0] * K + kbase, La + tid * 16);
    load_lds16(Ah + (size_t)garow[1] * K + kbase, La + 8192 + tid * 16);
    load_lds16(Bh + (size_t)gbrow0 * K + kbase, Lb + tid * 16);
    load_lds16(Bh + (size_t)gbrow1 * K + kbase, Lb + 8192 + tid * 16);
  };

  STAGE(0, 0);
  STAGE(0, 1);
  __syncthreads();

  for (int t = 0; t < KT; ++t) {
    const bool st = (t + 1 < KT);
    #pragma unroll
    for (int kk = 0; kk < 2; ++kk) {
      if (st) STAGE(t + 1, kk);
      const _Float16* La = &lds[t & 1][kk][0][0];
      const _Float16* Lb = &lds[t & 1][kk][1][0];
      half8 a[8], b[4];
      #pragma unroll
      for (int m = 0; m < 8; ++m) {
        int R = wr * 128 + m * 16 + fr;
        int s = fs ^ ((R >> 1) & 3);
        a[m] = *(const half8*)(La + R * 32 + s * 8);
      }
      #pragma unroll
      for (int n = 0; n < 4; ++n) {
        int R = wc * 64 + n * 16 + fr;
        int s = fs ^ ((R >> 1) & 3);
        b[n] = *(const half8*)(Lb + R * 32 + s * 8);
      }
      __builtin_amdgcn_s_setprio(1);
      #pragma unroll
      for (int m = 0; m < 8; ++m)
        #pragma unroll
        for (int n = 0; n < 4; ++n)
          acc[m][n] = __builtin_amdgcn_mfma_f32_16x16x32_f16(a[m], b[n], acc[m][n], 0, 0, 0);
      __builtin_amdgcn_s_setprio(0);
      if (st) asm volatile("s_waitcnt vmcnt(4)" ::: "memory");
      else    asm volatile("s_waitcnt vmcnt(0)" ::: "memory");
      __builtin_amdgcn_s_barrier();
    }
  }

  // epilogue: C/D layout col=lane&15, row=(lane>>4)*4+q  [m89/m91 verified]
  const int fq = fs << 2;
  #pragma unroll
  for (int m = 0; m < 8; ++m) {
    #pragma unroll
    for (int n = 0; n < 4; ++n) {
      int gn = n0 + wc * 64 + n * 16 + fr;
      float bv = bias[gn];
      #pragma unroll
      for (int q = 0; q < 4; ++q) {
        int gm = m0 + wr * 128 + m * 16 + fq + q;
        if (gm < M) {
          float val = acc[m][n][q] + bv;
          int region = gn >> 9;          // block-uniform (region 512, tile 256)
          int d = gn & 511;
          if (region == 0) {
            Qh[(size_t)gm * 512 + d] = (_Float16)val;
          } else {
            float s = fminf(fmaxf(val * KQ_SCALE, -127.f), 127.f);
            signed char c = (signed char)__float2int_rn(s);
            size_t idx = (size_t)gm * 1024 + ((d >> 3) << 4) + (d & 7)
                       + (region == 2 ? 8 : 0);
            ((signed char*)KV8)[idx] = c;
          }
        }
      }
    }
  }
}

// ---------------- FF GEMM (NT) 128x128, BK=32, 256 thr (R6 structure) --------------
// 140 regs -> 3 blocks/CU (inter-block overlap); grid x = n-tiles fastest.
__global__ __launch_bounds__(256)
void k_gemm128(const _Float16* __restrict__ Ah, const _Float16* __restrict__ Bh,
               const float* __restrict__ bias, float* __restrict__ C,
               int M, int N, int K) {
  __shared__ _Float16 As[128 * 32];
  __shared__ _Float16 Bs[128 * 32];
  const int tid = threadIdx.x;
  const int m0 = blockIdx.y * 128;
  const int n0 = blockIdx.x * 128;
  const int wid = tid >> 6, lane = tid & 63;
  const int wr = wid >> 1, wc = wid & 1;

  floatx4 acc[4][4];
  #pragma unroll
  for (int i = 0; i < 4; ++i)
    #pragma unroll
    for (int j = 0; j < 4; ++j)
      #pragma unroll
      for (int q = 0; q < 4; ++q) acc[i][j][q] = 0.f;

  const int srow = tid >> 2;
  const int sslot = tid & 3;
  const int fr = lane & 15;
  const int fslot = lane >> 4;

  int garow0 = m0 + srow;       if (garow0 >= M) garow0 = M - 1;
  int garow1 = m0 + srow + 64;  if (garow1 >= M) garow1 = M - 1;
  const int asl0 = sslot ^ ((srow >> 1) & 3);
  const int asl1 = sslot ^ (((srow + 64) >> 1) & 3);
  const int gbrow0 = n0 + srow, gbrow1 = n0 + srow + 64;

  for (int k0 = 0; k0 < K; k0 += 32) {
    load_lds16(Ah + (size_t)garow0 * K + k0 + asl0 * 8, (char*)As + wid * 1024);
    load_lds16(Ah + (size_t)garow1 * K + k0 + asl1 * 8, (char*)As + 4096 + wid * 1024);
    load_lds16(Bh + (size_t)gbrow0 * K + k0 + asl0 * 8, (char*)Bs + wid * 1024);
    load_lds16(Bh + (size_t)gbrow1 * K + k0 + asl1 * 8, (char*)Bs + 4096 + wid * 1024);
    __syncthreads();

    half8 a[4], b[4];
    #pragma unroll
    for (int m = 0; m < 4; ++m) {
      int R = wr * 64 + m * 16 + fr;
      a[m] = *(const half8*)(As + R * 32 + ((fslot ^ ((R >> 1) & 3)) << 3));
    }
    #pragma unroll
    for (int n = 0; n < 4; ++n) {
      int R = wc * 64 + n * 16 + fr;
      b[n] = *(const half8*)(Bs + R * 32 + ((fslot ^ ((R >> 1) & 3)) << 3));
    }
    #pragma unroll
    for (int m = 0; m < 4; ++m)
      #pragma unroll
      for (int n = 0; n < 4; ++n)
        acc[m][n] = __builtin_amdgcn_mfma_f32_16x16x32_f16(a[m], b[n], acc[m][n], 0, 0, 0);
    __syncthreads();
  }

  const int fq = (lane >> 4) << 2;
  #pragma unroll
  for (int m = 0; m < 4; ++m) {
    #pragma unroll
    for (int n = 0; n < 4; ++n) {
      int gn = n0 + wc * 64 + n * 16 + fr;
      float bv = bias[gn];
      #pragma unroll
      for (int q = 0; q < 4; ++q) {
        int gm = m0 + wr * 64 + m * 16 + fq + q;
        if (gm < M)
          C[(size_t)gm * N + gn] = acc[m][n][q] + bv;
      }
    }
  }
}

// ---------------- attention aggregation: one wave per receiver ----------------
// Qh [N][512] f16 ; KV8 [N][1024] int8 interleaved (chunk c: 8B K | 8B V, dims 8c..).
// ONE 16B/lane gather per edge (1KB/wave, fully coalesced). Depth-4 pipeline.
__global__ __launch_bounds__(256)
void k_attn(const _Float16* __restrict__ Qh, const unsigned char* __restrict__ KV8,
            const int* __restrict__ off, const int* __restrict__ srt,
            _Float16* __restrict__ msg) {
  int r = blockIdx.x * 4 + (threadIdx.x >> 6);
  if (r >= NN) return;
  int lane = threadIdx.x & 63;
  int qoff = lane * 8;           // lane covers dims lane*8 .. lane*8+7

  half8 qh = *(const half8*)(Qh + (size_t)r * 512 + qoff);
  float q[8];
  #pragma unroll
  for (int i = 0; i < 8; ++i) q[i] = (float)qh[i] * 0.125f * KQ_DEQ;  // 1/sqrt(64) * K dequant

  float denom = 0.f;
  float acc[8];
  #pragma unroll
  for (int i = 0; i < 8; ++i) acc[i] = 0.f;

  int e0 = off[r], e1 = off[r + 1];
  if (e1 <= e0) {
    half8 z = {};
    *(half8*)(msg + (size_t)r * 512 + qoff) = z;
    return;
  }

  auto gload = [&](uint4& kv, int s) {
    kv = *(const uint4*)(KV8 + (size_t)s * 1024 + lane * 16);
  };
  auto consume = [&](uint4 kv) {
    int xw = (int)kv.x, yw = (int)kv.y;       // K bytes 0-7
    float p = 0.f;
    p += q[0] * (float)((xw << 24) >> 24);
    p += q[1] * (float)((xw << 16) >> 24);
    p += q[2] * (float)((xw << 8) >> 24);
    p += q[3] * (float)(xw >> 24);
    p += q[4] * (float)((yw << 24) >> 24);
    p += q[5] * (float)((yw << 16) >> 24);
    p += q[6] * (float)((yw << 8) >> 24);
    p += q[7] * (float)(yw >> 24);
    p += __shfl_xor(p, 1);
    p += __shfl_xor(p, 2);
    p += __shfl_xor(p, 4);
    float w = __expf(p);   // exact softmax sans max-shift (scores ~N(0,1))
    denom += w;
    int vx = (int)kv.z, vy = (int)kv.w;       // V bytes 8-15
    acc[0] += w * (float)((vx << 24) >> 24);
    acc[1] += w * (float)((vx << 16) >> 24);
    acc[2] += w * (float)((vx << 8) >> 24);
    acc[3] += w * (float)(vx >> 24);
    acc[4] += w * (float)((vy << 24) >> 24);
    acc[5] += w * (float)((vy << 16) >> 24);
    acc[6] += w * (float)((vy << 8) >> 24);
    acc[7] += w * (float)(vy >> 24);
  };
  auto sidx = [&](int e) { return srt[e < e1 ? e : e1 - 1]; };

  uint4 b0, b1, b2, b3;
  gload(b0, sidx(e0));
  gload(b1, sidx(e0 + 1));
  gload(b2, sidx(e0 + 2));
  gload(b3, sidx(e0 + 3));
  int sn0 = sidx(e0 + 4), sn1 = sidx(e0 + 5), sn2 = sidx(e0 + 6), sn3 = sidx(e0 + 7);

  int e = e0;
  for (; e + 4 <= e1; e += 4) {
    consume(b0); gload(b0, sn0);
    consume(b1); gload(b1, sn1);
    consume(b2); gload(b2, sn2);
    consume(b3); gload(b3, sn3);
    sn0 = sidx(e + 8); sn1 = sidx(e + 9); sn2 = sidx(e + 10); sn3 = sidx(e + 11);
  }
  int rem = e1 - e;
  if (rem > 0) consume(b0);
  if (rem > 1) consume(b1);
  if (rem > 2) consume(b2);

  float inv = KQ_DEQ / denom;   // fold V dequant into the normalization
  half8 oh;
  #pragma unroll
  for (int i = 0; i < 8; ++i) oh[i] = (_Float16)(acc[i] * inv);
  *(half8*)(msg + (size_t)r * 512 + qoff) = oh;
}

// ---------------- launcher ----------------
extern "C" void kernel_launch(void* const* d_in, const int* in_sizes, int n_in,
                              void* d_out, int out_size, void* d_ws, size_t ws_size,
                              hipStream_t stream) {
  const float* x     = (const float*)d_in[0];
  const void*  edge  = d_in[1];
  const float* W_qkv = (const float*)d_in[2];
  const float* b_qkv = (const float*)d_in[3];
  const float* W_ff  = (const float*)d_in[4];
  const float* b_ff  = (const float*)d_in[5];
  float* out = (float*)d_out;

  char* ws = (char*)d_ws;
  _Float16* Qh = (_Float16*)(ws + OFF_QH);
  unsigned char* KV8 = (unsigned char*)(ws + OFF_KV8);
  _Float16* msgb = (_Float16*)(ws + OFF_MSG);   // aliases xh (disjoint lifetimes)
  _Float16* xh   = (_Float16*)(ws + OFF_MSG);
  int* srt  = (int*)(ws + OFF_SRT);
  int* deg  = (int*)(ws + OFF_DEG);
  int* offa = (int*)(ws + OFF_OFFA);
  int* cur  = (int*)(ws + OFF_CUR);
  int* flag = (int*)(ws + OFF_FLAG);
  _Float16* wqh = (_Float16*)(ws + OFF_WQH);
  _Float16* wfh = (_Float16*)(ws + OFF_WFH);

  hipMemsetAsync(deg, 0, NN * sizeof(int), stream);
  k_detect64<<<1, 64, 0, stream>>>(edge, flag);

  // f32 -> f16 conversions (x, W_qkv, W_ff)
  k_cvt<<<(NN * DEMB / 8 + 255) / 256, 256, 0, stream>>>(x, xh, NN * DEMB / 8);
  k_cvt<<<(QKV_OUT * DEMB / 8 + 255) / 256, 256, 0, stream>>>(W_qkv, wqh, QKV_OUT * DEMB / 8);
  k_cvt<<<(DEMB * DEMB / 8 + 255) / 256, 256, 0, stream>>>(W_ff, wfh, DEMB * DEMB / 8);

  // QKV projection (grid 1176 = 147*8 GEMM blocks) + fused edge histogram
  // (1563 extra blocks run in the GEMM's scheduling tail).
  const int gemmBlocks = 1176;
  const int histoBlocks = (NE + 511) / 512;     // 1563
  k_qkv<<<gemmBlocks + histoBlocks, 512, 0, stream>>>(
      xh, wqh, b_qkv, Qh, KV8, edge, flag, deg,
      NN, QKV_OUT, DEMB, 6, gemmBlocks);

  k_scan<<<1, 1024, 0, stream>>>(deg, offa, cur, NN);
  k_scatter<<<(NE + 255) / 256, 256, 0, stream>>>(edge, flag, cur, srt);

  // per-receiver online softmax + weighted V aggregation -> f16 [N,512]
  k_attn<<<(NN + 3) / 4, 256, 0, stream>>>(Qh, KV8, offa, srt, msgb);

  // output projection: [N,512] x [512,512]^T -> f32 d_out (128^2 tile, 3 blocks/CU)
  k_gemm128<<<dim3(4, 391), 256, 0, stream>>>(
      msgb, wfh, b_ff, out, NN, DEMB, DEMB);
}

// Round 14
// 542.814 us; speedup vs baseline: 1.0833x; 1.0531x over previous
//
#include <hip/hip_runtime.h>

static constexpr int NN = 50000;      // nodes
static constexpr int NE = 800000;     // edges
static constexpr int DEMB = 512;
static constexpr int QKV_OUT = 1536;  // (2*64+64)*8

typedef _Float16 half8 __attribute__((ext_vector_type(8)));
typedef float floatx4 __attribute__((ext_vector_type(4)));

// K/V int8 quantization: values ~ N(0,1); clamp at 5.5 sigma (P ~ 4e-8)
#define KQ_SCALE (127.0f / 5.5f)
#define KQ_DEQ   (5.5f / 127.0f)

// ---------------- workspace layout (bytes) ----------------
static constexpr size_t OFF_QH   = 0;                    // N*512 f16 = 51,200,000
static constexpr size_t OFF_KV8  = 51200000;             // N*1024 i8 = 51,200,000 (K/V interleaved 8B:8B)
static constexpr size_t OFF_MSG  = 102400000;            // N*512 f16 = 51,200,000 (aliases xh)
static constexpr size_t OFF_SRT  = 153600000;            // E i32     =  3,200,000
static constexpr size_t OFF_DEG  = 156800000;            // N i32
static constexpr size_t OFF_OFFA = 157000000;            // (N+1) i32
static constexpr size_t OFF_CUR  = 157200064;            // N i32
static constexpr size_t OFF_FLAG = 157400064;            // 1 i32
static constexpr size_t OFF_WQH  = 157400128;            // 1536*512 f16 = 1,572,864
static constexpr size_t OFF_WFH  = 158972992;            // 512*512 f16  =   524,288

typedef __attribute__((address_space(1))) const void* gas_ptr;
typedef __attribute__((address_space(3))) void* lds_ptr_t;

__device__ __forceinline__ void load_lds16(const void* g, void* l) {
  __builtin_amdgcn_global_load_lds((gas_ptr)g, (lds_ptr_t)l, 16, 0, 0);
}

// ---------------- f32 -> f16 convert ----------------
__global__ __launch_bounds__(256)
void k_cvt(const float* __restrict__ in, _Float16* __restrict__ out, int n8) {
  int i = blockIdx.x * 256 + threadIdx.x;
  if (i < n8) {
    floatx4 a = *(const floatx4*)(in + (size_t)i * 8);
    floatx4 b = *(const floatx4*)(in + (size_t)i * 8 + 4);
    half8 h;
    #pragma unroll
    for (int q = 0; q < 4; ++q) { h[q] = (_Float16)a[q]; h[q + 4] = (_Float16)b[q]; }
    *(half8*)(out + (size_t)i * 8) = h;
  }
}

// ---------------- edge dtype detection (int32 vs int64) ----------------
__global__ __launch_bounds__(64)
void k_detect64(const void* __restrict__ edge, int* __restrict__ flag) {
  if (threadIdx.x == 0) {
    const int* p = (const int*)edge;
    int is64 = 1;
    for (int i = 0; i < 16; ++i) if (p[2 * i + 1] != 0) is64 = 0;
    *flag = is64;
  }
}

__device__ __forceinline__ int edge_at(const void* edge, int row, int e, int is64) {
  if (is64) return (int)((const long long*)edge)[(size_t)row * NE + e];
  return ((const int*)edge)[(size_t)row * NE + e];
}

// ---------------- CSR build (scan + scatter; histo fused into QKV GEMM) ----
__global__ __launch_bounds__(1024)
void k_scan(const int* __restrict__ deg, int* __restrict__ off,
            int* __restrict__ cur, int n) {
  __shared__ int sums[1024];
  int tid = threadIdx.x;
  int per = (n + 1023) >> 10;
  int start = tid * per;
  int end = start + per; if (end > n) end = n;
  int s = 0;
  for (int i = start; i < end; ++i) s += deg[i];
  sums[tid] = s;
  __syncthreads();
  for (int d = 1; d < 1024; d <<= 1) {
    int v = (tid >= d) ? sums[tid - d] : 0;
    __syncthreads();
    sums[tid] += v;
    __syncthreads();
  }
  int run = (tid == 0) ? 0 : sums[tid - 1];
  for (int i = start; i < end; ++i) {
    off[i] = run; cur[i] = run; run += deg[i];
  }
  if (tid == 0) off[n] = sums[1023];
}

__global__ __launch_bounds__(256)
void k_scatter(const void* __restrict__ edge, const int* __restrict__ flag,
               int* __restrict__ cur, int* __restrict__ srt) {
  int e = blockIdx.x * 256 + threadIdx.x;
  if (e < NE) {
    int is64 = *flag;
    int r = edge_at(edge, 1, e, is64);
    int s = edge_at(edge, 0, e, is64);
    int pos = atomicAdd(&cur[r], 1);
    srt[pos] = s;
  }
}

// ---------------- GEMM (NT): B-in-LDS-once, A global->reg, ZERO K-loop barriers ----
// C[m,n] = sum_k A[m,k]*B[n,k] + bias[n]; A,B f16 row-major; K=512.
// Block: 512 threads (8 waves), tile 512m x 128n; wave w owns rows [w*64, w*64+64).
// B-panel [128 n][512 k] loaded ONCE into 128KB LDS (gload_lds, linear dest;
// 16B-chunk swizzle: stored chunk sc holds global chunk sc^(row&7) -> reads are
// bank-balanced, same class as the R6-measured-conflict-free pattern).
// A fragments load DIRECTLY global->VGPR: a-frag touches 16 rows x 64B = full
// cache lines (perfectly coalesced), 1-step register prefetch hides L2/L3 latency.
// K-loop: 16 steps x {4 global a-loads (t+1), 8 swizzled ds_read_b128, 32 MFMA},
// NO barriers/waitcnt — waves free-run; compiler emits granular lgkm/vmcnt.
// Accumulation order per acc element: ascending k (identical to prior kernels).
// MODE 0: QKV epilogue + FUSED edge histogram in trailing blocks.
// MODE 1: plain f32 C.
template<int MODE>
__global__ __launch_bounds__(512, 2)
void k_gemmB(const _Float16* __restrict__ Ah, const _Float16* __restrict__ Bh,
             const float* __restrict__ bias,
             void* __restrict__ out0, void* __restrict__ out1,
             const void* __restrict__ edge, const int* __restrict__ flag,
             int* __restrict__ deg,
             int M, int N, int K, int nxt, int gemmBlocks) {
  __shared__ _Float16 Bs[128 * 512];   // 128 KiB
  const int tid = threadIdx.x;

  if (MODE == 0 && blockIdx.x >= gemmBlocks) {   // fused histogram tail
    int e = (blockIdx.x - gemmBlocks) * 512 + tid;
    if (e < NE) {
      int r = edge_at(edge, 1, e, *flag);
      atomicAdd(&deg[r], 1);
    }
    return;
  }

  // XCD-chunked swizzle (gemmBlocks multiple of 8), n-fastest inside chunk
  const int cpx = gemmBlocks >> 3;
  const int w = (blockIdx.x & 7) * cpx + (blockIdx.x >> 3);
  const int m0 = (w / nxt) * 512;
  const int n0 = (w % nxt) * 128;

  const int wid = tid >> 6, lane = tid & 63;
  const int fr = lane & 15;
  const int fs = lane >> 4;                 // 0..3

  // ---- B panel -> LDS (once). 8192 chunks of 16B; linear dest, src pre-swizzled.
  #pragma unroll
  for (int it = 0; it < 16; ++it) {
    int L = it * 512 + tid;                 // chunk linear id
    int row = L >> 6, sc = L & 63;
    int c = sc ^ (row & 7);
    load_lds16(Bh + (size_t)(n0 + row) * K + c * 8, (char*)Bs + (size_t)L * 16);
  }

  floatx4 acc[4][8];
  #pragma unroll
  for (int m = 0; m < 4; ++m)
    #pragma unroll
    for (int n = 0; n < 8; ++n)
      #pragma unroll
      for (int q = 0; q < 4; ++q) acc[m][n][q] = 0.f;

  // per-thread A row indices (clamped; stores masked)
  int arow[4];
  #pragma unroll
  for (int m = 0; m < 4; ++m) {
    int r = m0 + wid * 64 + m * 16 + fr;
    arow[m] = r < M ? r : M - 1;
  }

  __syncthreads();   // B resident (drains the gload_lds); ONLY barrier.

  auto LDA = [&](half8* dst, int t) {
    const int k0 = t * 32 + fs * 8;
    #pragma unroll
    for (int m = 0; m < 4; ++m)
      dst[m] = *(const half8*)(Ah + (size_t)arow[m] * K + k0);
  };

  half8 a[4], an[4];
  LDA(a, 0);
  for (int t = 0; t < 16; ++t) {
    if (t + 1 < 16) LDA(an, t + 1);
    half8 b[8];
    #pragma unroll
    for (int n = 0; n < 8; ++n) {
      int R = n * 16 + fr;
      int c = (t * 4 + fs) ^ (R & 7);
      b[n] = *(const half8*)(Bs + R * 512 + c * 8);
    }
    #pragma unroll
    for (int m = 0; m < 4; ++m)
      #pragma unroll
      for (int n = 0; n < 8; ++n)
        acc[m][n] = __builtin_amdgcn_mfma_f32_16x16x32_f16(a[m], b[n], acc[m][n], 0, 0, 0);
    #pragma unroll
    for (int m = 0; m < 4; ++m) a[m] = an[m];
  }

  // epilogue: C/D layout col=lane&15, row=(lane>>4)*4+q  [m89/m91 verified]
  const int fq = fs << 2;
  #pragma unroll
  for (int m = 0; m < 4; ++m) {
    #pragma unroll
    for (int n = 0; n < 8; ++n) {
      int gn = n0 + n * 16 + fr;
      float bv = bias[gn];
      #pragma unroll
      for (int q = 0; q < 4; ++q) {
        int gm = m0 + wid * 64 + m * 16 + fq + q;
        if (gm < M) {
          float val = acc[m][n][q] + bv;
          if (MODE == 0) {
            int region = gn >> 9;          // block-uniform (n-tile 128 within 512)
            int d = gn & 511;
            if (region == 0) {
              ((_Float16*)out0)[(size_t)gm * 512 + d] = (_Float16)val;
            } else {
              float s = fminf(fmaxf(val * KQ_SCALE, -127.f), 127.f);
              signed char c = (signed char)__float2int_rn(s);
              size_t idx = (size_t)gm * 1024 + ((d >> 3) << 4) + (d & 7)
                         + (region == 2 ? 8 : 0);
              ((signed char*)out1)[idx] = c;
            }
          } else {
            ((float*)out0)[(size_t)gm * N + gn] = val;
          }
        }
      }
    }
  }
}

// ---------------- attention aggregation: one wave per receiver ----------------
// Qh [N][512] f16 ; KV8 [N][1024] int8 interleaved (chunk c: 8B K | 8B V).
// ONE 16B/lane gather per edge (1KB/wave, fully coalesced). Depth-4 pipeline.
__global__ __launch_bounds__(256)
void k_attn(const _Float16* __restrict__ Qh, const unsigned char* __restrict__ KV8,
            const int* __restrict__ off, const int* __restrict__ srt,
            _Float16* __restrict__ msg) {
  int r = blockIdx.x * 4 + (threadIdx.x >> 6);
  if (r >= NN) return;
  int lane = threadIdx.x & 63;
  int qoff = lane * 8;           // lane covers dims lane*8 .. lane*8+7

  half8 qh = *(const half8*)(Qh + (size_t)r * 512 + qoff);
  float q[8];
  #pragma unroll
  for (int i = 0; i < 8; ++i) q[i] = (float)qh[i] * 0.125f * KQ_DEQ;  // 1/sqrt(64) * K dequant

  float denom = 0.f;
  float acc[8];
  #pragma unroll
  for (int i = 0; i < 8; ++i) acc[i] = 0.f;

  int e0 = off[r], e1 = off[r + 1];
  if (e1 <= e0) {
    half8 z = {};
    *(half8*)(msg + (size_t)r * 512 + qoff) = z;
    return;
  }

  auto gload = [&](uint4& kv, int s) {
    kv = *(const uint4*)(KV8 + (size_t)s * 1024 + lane * 16);
  };
  auto consume = [&](uint4 kv) {
    int xw = (int)kv.x, yw = (int)kv.y;       // K bytes 0-7
    float p = 0.f;
    p += q[0] * (float)((xw << 24) >> 24);
    p += q[1] * (float)((xw << 16) >> 24);
    p += q[2] * (float)((xw << 8) >> 24);
    p += q[3] * (float)(xw >> 24);
    p += q[4] * (float)((yw << 24) >> 24);
    p += q[5] * (float)((yw << 16) >> 24);
    p += q[6] * (float)((yw << 8) >> 24);
    p += q[7] * (float)(yw >> 24);
    p += __shfl_xor(p, 1);
    p += __shfl_xor(p, 2);
    p += __shfl_xor(p, 4);
    float w = __expf(p);   // exact softmax sans max-shift (scores ~N(0,1))
    denom += w;
    int vx = (int)kv.z, vy = (int)kv.w;       // V bytes 8-15
    acc[0] += w * (float)((vx << 24) >> 24);
    acc[1] += w * (float)((vx << 16) >> 24);
    acc[2] += w * (float)((vx << 8) >> 24);
    acc[3] += w * (float)(vx >> 24);
    acc[4] += w * (float)((vy << 24) >> 24);
    acc[5] += w * (float)((vy << 16) >> 24);
    acc[6] += w * (float)((vy << 8) >> 24);
    acc[7] += w * (float)(vy >> 24);
  };
  auto sidx = [&](int e) { return srt[e < e1 ? e : e1 - 1]; };

  uint4 b0, b1, b2, b3;
  gload(b0, sidx(e0));
  gload(b1, sidx(e0 + 1));
  gload(b2, sidx(e0 + 2));
  gload(b3, sidx(e0 + 3));
  int sn0 = sidx(e0 + 4), sn1 = sidx(e0 + 5), sn2 = sidx(e0 + 6), sn3 = sidx(e0 + 7);

  int e = e0;
  for (; e + 4 <= e1; e += 4) {
    consume(b0); gload(b0, sn0);
    consume(b1); gload(b1, sn1);
    consume(b2); gload(b2, sn2);
    consume(b3); gload(b3, sn3);
    sn0 = sidx(e + 8); sn1 = sidx(e + 9); sn2 = sidx(e + 10); sn3 = sidx(e + 11);
  }
  int rem = e1 - e;
  if (rem > 0) consume(b0);
  if (rem > 1) consume(b1);
  if (rem > 2) consume(b2);

  float inv = KQ_DEQ / denom;   // fold V dequant into the normalization
  half8 oh;
  #pragma unroll
  for (int i = 0; i < 8; ++i) oh[i] = (_Float16)(acc[i] * inv);
  *(half8*)(msg + (size_t)r * 512 + qoff) = oh;
}

// ---------------- launcher ----------------
extern "C" void kernel_launch(void* const* d_in, const int* in_sizes, int n_in,
                              void* d_out, int out_size, void* d_ws, size_t ws_size,
                              hipStream_t stream) {
  const float* x     = (const float*)d_in[0];
  const void*  edge  = d_in[1];
  const float* W_qkv = (const float*)d_in[2];
  const float* b_qkv = (const float*)d_in[3];
  const float* W_ff  = (const float*)d_in[4];
  const float* b_ff  = (const float*)d_in[5];
  float* out = (float*)d_out;

  char* ws = (char*)d_ws;
  _Float16* Qh = (_Float16*)(ws + OFF_QH);
  unsigned char* KV8 = (unsigned char*)(ws + OFF_KV8);
  _Float16* msgb = (_Float16*)(ws + OFF_MSG);   // aliases xh (disjoint lifetimes)
  _Float16* xh   = (_Float16*)(ws + OFF_MSG);
  int* srt  = (int*)(ws + OFF_SRT);
  int* deg  = (int*)(ws + OFF_DEG);
  int* offa = (int*)(ws + OFF_OFFA);
  int* cur  = (int*)(ws + OFF_CUR);
  int* flag = (int*)(ws + OFF_FLAG);
  _Float16* wqh = (_Float16*)(ws + OFF_WQH);
  _Float16* wfh = (_Float16*)(ws + OFF_WFH);

  hipMemsetAsync(deg, 0, NN * sizeof(int), stream);
  k_detect64<<<1, 64, 0, stream>>>(edge, flag);

  // f32 -> f16 conversions (x, W_qkv, W_ff)
  k_cvt<<<(NN * DEMB / 8 + 255) / 256, 256, 0, stream>>>(x, xh, NN * DEMB / 8);
  k_cvt<<<(QKV_OUT * DEMB / 8 + 255) / 256, 256, 0, stream>>>(W_qkv, wqh, QKV_OUT * DEMB / 8);
  k_cvt<<<(DEMB * DEMB / 8 + 255) / 256, 256, 0, stream>>>(W_ff, wfh, DEMB * DEMB / 8);

  // QKV projection: 98 m-tiles (512) x 12 n-tiles (128) = 1176 = 147*8 GEMM blocks
  // + fused edge histogram in the scheduling tail.
  const int gemmBlocks = 1176;
  const int histoBlocks = (NE + 511) / 512;     // 1563
  k_gemmB<0><<<gemmBlocks + histoBlocks, 512, 0, stream>>>(
      xh, wqh, b_qkv, Qh, KV8, edge, flag, deg,
      NN, QKV_OUT, DEMB, 12, gemmBlocks);

  k_scan<<<1, 1024, 0, stream>>>(deg, offa, cur, NN);
  k_scatter<<<(NE + 255) / 256, 256, 0, stream>>>(edge, flag, cur, srt);

  // per-receiver online softmax + weighted V aggregation -> f16 [N,512]
  k_attn<<<(NN + 3) / 4, 256, 0, stream>>>(Qh, KV8, offa, srt, msgb);

  // output projection: 98 x 4 = 392 = 49*8 blocks
  k_gemmB<1><<<392, 512, 0, stream>>>(
      msgb, wfh, b_ff, out, nullptr, nullptr, nullptr, nullptr,
      NN, DEMB, DEMB, 4, 392);
}